// Round 1
// baseline (1847.059 us; speedup 1.0000x reference)
//
#include <hip/hip_runtime.h>

#define HID 64
#define N_GRAPHS_C 512

// ---------------- degree / normalization ----------------

__global__ void fill_deg(float* __restrict__ deg, int n) {
    int i = blockIdx.x * blockDim.x + threadIdx.x;
    if (i < n) deg[i] = 1.0f;  // self-loop contributes 1
}

__global__ void deg_accum(const int* __restrict__ dst, float* __restrict__ deg, int nE) {
    int e = blockIdx.x * blockDim.x + threadIdx.x;
    if (e < nE) atomicAdd(&deg[dst[e]], 1.0f);
}

__global__ void to_dinv(float* __restrict__ deg, int n) {
    int i = blockIdx.x * blockDim.x + threadIdx.x;
    if (i < n) deg[i] = 1.0f / sqrtf(deg[i]);  // deg >= 1 always (self-loop)
}

// ---------------- layer 1 matmul: A = x @ W1  ([N,3]x[3,64]) ----------------

__global__ void mm1(const float* __restrict__ x, const float* __restrict__ W1,
                    float* __restrict__ A, int n) {
    __shared__ float w[3 * HID];
    int t = threadIdx.x;
    if (t < 3 * HID) w[t] = W1[t];
    __syncthreads();
    int tid = blockIdx.x * blockDim.x + t;  // tid = node*64 + f (blockDim=256)
    int node = tid >> 6, f = tid & 63;
    if (node < n) {
        float x0 = x[node * 3 + 0], x1 = x[node * 3 + 1], x2 = x[node * 3 + 2];
        A[tid] = x0 * w[f] + x1 * w[HID + f] + x2 * w[2 * HID + f];
    }
}

// ---------------- edge scatter: B[dst] += A[src] * dinv[src]*dinv[dst] ----------------
// 16 threads per edge, 4 features (float4) per thread.

__global__ void scatter_edges(const float* __restrict__ A, const float* __restrict__ dinv,
                              const int* __restrict__ src, const int* __restrict__ dst,
                              float* __restrict__ B, int nE) {
    int tid = blockIdx.x * blockDim.x + threadIdx.x;
    int e = tid >> 4;
    int j = (tid & 15) * 4;
    if (e < nE) {
        int s = src[e], d = dst[e];
        float norm = dinv[s] * dinv[d];
        const float4 a = *(const float4*)(A + (size_t)s * HID + j);
        float* bp = B + (size_t)d * HID + j;
        atomicAdd(bp + 0, a.x * norm);
        atomicAdd(bp + 1, a.y * norm);
        atomicAdd(bp + 2, a.z * norm);
        atomicAdd(bp + 3, a.w * norm);
    }
}

// ---------------- self-loop + bias + relu (in place on B) ----------------

__global__ void bias_relu_self(float* __restrict__ B, const float* __restrict__ A,
                               const float* __restrict__ dinv, const float* __restrict__ b,
                               int n) {
    int tid = blockIdx.x * blockDim.x + threadIdx.x;
    int node = tid >> 6, f = tid & 63;
    if (node < n) {
        float di = dinv[node];
        float v = B[tid] + A[tid] * di * di + b[f];
        B[tid] = v > 0.0f ? v : 0.0f;
    }
}

// ---------------- layer 2 matmul: A = H @ W2  ([N,64]x[64,64]) ----------------

#define MM2_NODES 16
__global__ void mm2(const float* __restrict__ H, const float* __restrict__ W2,
                    float* __restrict__ A, int n) {
    __shared__ float w[HID * HID];        // 16 KB
    __shared__ float h[MM2_NODES * HID];  // 4 KB
    int t = threadIdx.x;  // 256 threads
    for (int i = t; i < HID * HID; i += 256) w[i] = W2[i];
    int base = blockIdx.x * MM2_NODES;
    for (int i = t; i < MM2_NODES * HID; i += 256) {
        int node = base + (i >> 6);
        h[i] = (node < n) ? H[(size_t)node * HID + (i & 63)] : 0.0f;
    }
    __syncthreads();
    int f = t & 63, g = t >> 6;  // 4 groups x 4 nodes each
    float acc0 = 0.f, acc1 = 0.f, acc2 = 0.f, acc3 = 0.f;
    #pragma unroll 8
    for (int k = 0; k < HID; ++k) {
        float wk = w[k * HID + f];
        acc0 += h[(g * 4 + 0) * HID + k] * wk;
        acc1 += h[(g * 4 + 1) * HID + k] * wk;
        acc2 += h[(g * 4 + 2) * HID + k] * wk;
        acc3 += h[(g * 4 + 3) * HID + k] * wk;
    }
    float accs[4] = {acc0, acc1, acc2, acc3};
    #pragma unroll
    for (int j = 0; j < 4; ++j) {
        int node = base + g * 4 + j;
        if (node < n) A[(size_t)node * HID + f] = accs[j];
    }
}

// ---------------- global mean pool (batch is sorted) ----------------
// Each wave (64 lanes = 64 features) walks 64 consecutive nodes, accumulating
// locally and flushing with an atomic only when the graph id changes.

__global__ void pool(const float* __restrict__ H, const int* __restrict__ batch,
                     float* __restrict__ pooled, float* __restrict__ counts, int n) {
    int f = threadIdx.x & 63, g = threadIdx.x >> 6;
    int start = (blockIdx.x * 4 + g) * 64;
    if (start >= n) return;
    int end = min(start + 64, n);
    int cur = batch[start];
    float acc = 0.0f, cnt = 0.0f;
    for (int i = start; i < end; ++i) {
        int bg = batch[i];
        if (bg != cur) {
            atomicAdd(&pooled[cur * HID + f], acc);
            if (f == 0) atomicAdd(&counts[cur], cnt);
            acc = 0.0f; cnt = 0.0f; cur = bg;
        }
        acc += H[(size_t)i * HID + f];
        cnt += 1.0f;
    }
    atomicAdd(&pooled[cur * HID + f], acc);
    if (f == 0) atomicAdd(&counts[cur], cnt);
}

__global__ void finalize(const float* __restrict__ pooled, const float* __restrict__ counts,
                         float* __restrict__ out, int total) {
    int tid = blockIdx.x * blockDim.x + threadIdx.x;
    if (tid < total) {
        float c = counts[tid >> 6];
        out[tid] = pooled[tid] / fmaxf(c, 1.0f);
    }
}

// ---------------- launcher ----------------

extern "C" void kernel_launch(void* const* d_in, const int* in_sizes, int n_in,
                              void* d_out, int out_size, void* d_ws, size_t ws_size,
                              hipStream_t stream) {
    const float* x  = (const float*)d_in[0];
    const float* W1 = (const float*)d_in[1];
    const float* b1 = (const float*)d_in[2];
    const float* W2 = (const float*)d_in[3];
    const float* b2 = (const float*)d_in[4];
    const int*   ei = (const int*)d_in[5];    // int inputs arrive as int32
    const int*   batch = (const int*)d_in[6];

    const int n  = in_sizes[0] / 3;   // 100000
    const int nE = in_sizes[5] / 2;   // 1000000
    const int* src = ei;
    const int* dst = ei + nE;

    float* ws     = (float*)d_ws;
    float* dinv   = ws;                          // n floats (deg, then dinv in place)
    float* A      = ws + n;                      // n*64 (16B-aligned: n*4 % 16 == 0)
    float* B      = A + (size_t)n * HID;         // n*64
    float* pooled = B + (size_t)n * HID;         // 512*64
    float* counts = pooled + N_GRAPHS_C * HID;   // 512

    const int BT = 256;
    const int gridNode   = (n + BT - 1) / BT;
    const int gridEdge   = (nE + BT - 1) / BT;
    const int gridNF     = (n * HID + BT - 1) / BT;        // one thread per (node,feature)
    const int gridScat   = ((nE * 16) + BT - 1) / BT;      // 16 threads per edge
    const int gridMM2    = (n + MM2_NODES - 1) / MM2_NODES;
    const int gridPool   = (n + BT - 1) / BT;
    const int gridFin    = (N_GRAPHS_C * HID + BT - 1) / BT;

    // degree / dinv
    fill_deg<<<gridNode, BT, 0, stream>>>(dinv, n);
    deg_accum<<<gridEdge, BT, 0, stream>>>(dst, dinv, nE);
    to_dinv<<<gridNode, BT, 0, stream>>>(dinv, n);

    // zero accumulators (ws is poisoned every launch)
    hipMemsetAsync(B, 0, (size_t)n * HID * sizeof(float), stream);
    hipMemsetAsync(pooled, 0, (size_t)(N_GRAPHS_C * HID + N_GRAPHS_C) * sizeof(float), stream);

    // layer 1
    mm1<<<gridNF, BT, 0, stream>>>(x, W1, A, n);
    scatter_edges<<<gridScat, BT, 0, stream>>>(A, dinv, src, dst, B, nE);
    bias_relu_self<<<gridNF, BT, 0, stream>>>(B, A, dinv, b1, n);

    // layer 2
    mm2<<<gridMM2, BT, 0, stream>>>(B, W2, A, n);
    hipMemsetAsync(B, 0, (size_t)n * HID * sizeof(float), stream);
    scatter_edges<<<gridScat, BT, 0, stream>>>(A, dinv, src, dst, B, nE);
    bias_relu_self<<<gridNF, BT, 0, stream>>>(B, A, dinv, b2, n);

    // pool + finalize
    pool<<<gridPool, BT, 0, stream>>>(B, batch, pooled, counts, n);
    finalize<<<gridFin, BT, 0, stream>>>(pooled, counts, (float*)d_out, N_GRAPHS_C * HID);
}

// Round 2
// 467.761 us; speedup vs baseline: 3.9487x; 3.9487x over previous
//
#include <hip/hip_runtime.h>

#define HID 64
#define N_GRAPHS_C 512
#define SCAN_BLK 256

// ---------------- CSR build ----------------

__global__ void count_deg(const int* __restrict__ dst, int* __restrict__ cnt, int nE) {
    int e = blockIdx.x * blockDim.x + threadIdx.x;
    if (e < nE) atomicAdd(&cnt[dst[e]], 1);
}

__global__ void dinv_from_cnt(const int* __restrict__ cnt, float* __restrict__ dinv, int n) {
    int i = blockIdx.x * blockDim.x + threadIdx.x;
    if (i < n) dinv[i] = rsqrtf((float)(cnt[i] + 1));  // +1 self-loop; deg >= 1
}

// exclusive scan, block-level (256/block) + block sums
__global__ void scan1(const int* __restrict__ cnt, int* __restrict__ off,
                      int* __restrict__ bsums, int n) {
    __shared__ int tmp[SCAN_BLK];
    int t = threadIdx.x;
    int i = blockIdx.x * SCAN_BLK + t;
    int v = (i < n) ? cnt[i] : 0;
    tmp[t] = v;
    __syncthreads();
    for (int d = 1; d < SCAN_BLK; d <<= 1) {
        int add = (t >= d) ? tmp[t - d] : 0;
        __syncthreads();
        tmp[t] += add;
        __syncthreads();
    }
    if (i < n) off[i] = tmp[t] - v;  // exclusive
    if (t == SCAN_BLK - 1) bsums[blockIdx.x] = tmp[t];
}

// exclusive scan of block sums (nb <= 512), single block of 512
__global__ void scan2(int* __restrict__ bsums, int nb) {
    __shared__ int tmp[512];
    int t = threadIdx.x;
    int v = (t < nb) ? bsums[t] : 0;
    tmp[t] = v;
    __syncthreads();
    for (int d = 1; d < 512; d <<= 1) {
        int add = (t >= d) ? tmp[t - d] : 0;
        __syncthreads();
        tmp[t] += add;
        __syncthreads();
    }
    if (t < nb) bsums[t] = tmp[t] - v;
}

__global__ void add_off(int* __restrict__ off, const int* __restrict__ bsums, int n) {
    int i = blockIdx.x * blockDim.x + threadIdx.x;
    if (i < n) off[i] += bsums[i >> 8];  // SCAN_BLK == 256
}

// bin sources by dst; off[d] becomes bucket END afterwards
__global__ void fill_csr(const int* __restrict__ src, const int* __restrict__ dst,
                         int* __restrict__ off, int* __restrict__ csr_src, int nE) {
    int e = blockIdx.x * blockDim.x + threadIdx.x;
    if (e < nE) {
        int d = dst[e];
        int pos = atomicAdd(&off[d], 1);
        csr_src[pos] = src[e];
    }
}

// ---------------- layer 1 matmul: A = (x @ W1) * dinv[node]  ----------------

__global__ void mm1(const float* __restrict__ x, const float* __restrict__ W1,
                    const float* __restrict__ dinv, float* __restrict__ A, int n) {
    __shared__ float w[3 * HID];
    int t = threadIdx.x;
    if (t < 3 * HID) w[t] = W1[t];
    __syncthreads();
    int tid = blockIdx.x * blockDim.x + t;
    int node = tid >> 6, f = tid & 63;
    if (node < n) {
        float x0 = x[node * 3 + 0], x1 = x[node * 3 + 1], x2 = x[node * 3 + 2];
        A[tid] = (x0 * w[f] + x1 * w[HID + f] + x2 * w[2 * HID + f]) * dinv[node];
    }
}

// ---------------- gather aggregation (replaces scatter + bias_relu_self) ----
// One wave per dst node; lane = feature. A is pre-scaled by dinv[src], so
// H[d] = relu( (sum_{s in N(d)} A[s] + A[d]) * dinv[d] + bias ).

__global__ void gather_nodes(const float* __restrict__ A, const float* __restrict__ dinv,
                             const int* __restrict__ csr_src, const int* __restrict__ off_end,
                             const int* __restrict__ cnt, const float* __restrict__ bias,
                             float* __restrict__ H, int n) {
    int node = blockIdx.x * (blockDim.x >> 6) + (threadIdx.x >> 6);
    int f = threadIdx.x & 63;
    if (node >= n) return;
    int end = off_end[node];
    int beg = end - cnt[node];
    float dd = dinv[node];
    float acc = A[(size_t)node * HID + f];  // self-loop (already *dinv[node])
    int s_next = (beg < end) ? csr_src[beg] : 0;
    for (int k = beg; k < end; ++k) {
        int s = s_next;
        s_next = (k + 1 < end) ? csr_src[k + 1] : 0;
        acc += A[(size_t)s * HID + f];
    }
    float v = acc * dd + bias[f];
    H[(size_t)node * HID + f] = v > 0.0f ? v : 0.0f;
}

// ---------------- layer 2 matmul: A = (H @ W2) * dinv[node] ----------------

#define MM2_NODES 16
__global__ void mm2(const float* __restrict__ H, const float* __restrict__ W2,
                    const float* __restrict__ dinv, float* __restrict__ A, int n) {
    __shared__ float w[HID * HID];        // 16 KB
    __shared__ float h[MM2_NODES * HID];  // 4 KB
    int t = threadIdx.x;  // 256
    for (int i = t; i < HID * HID; i += 256) w[i] = W2[i];
    int base = blockIdx.x * MM2_NODES;
    for (int i = t; i < MM2_NODES * HID; i += 256) {
        int node = base + (i >> 6);
        h[i] = (node < n) ? H[(size_t)node * HID + (i & 63)] : 0.0f;
    }
    __syncthreads();
    int f = t & 63, g = t >> 6;
    float acc0 = 0.f, acc1 = 0.f, acc2 = 0.f, acc3 = 0.f;
    #pragma unroll 8
    for (int k = 0; k < HID; ++k) {
        float wk = w[k * HID + f];
        acc0 += h[(g * 4 + 0) * HID + k] * wk;
        acc1 += h[(g * 4 + 1) * HID + k] * wk;
        acc2 += h[(g * 4 + 2) * HID + k] * wk;
        acc3 += h[(g * 4 + 3) * HID + k] * wk;
    }
    float accs[4] = {acc0, acc1, acc2, acc3};
    #pragma unroll
    for (int j = 0; j < 4; ++j) {
        int node = base + g * 4 + j;
        if (node < n) A[(size_t)node * HID + f] = accs[j] * dinv[node];
    }
}

// ---------------- global mean pool (batch sorted) ----------------

__global__ void pool(const float* __restrict__ H, const int* __restrict__ batch,
                     float* __restrict__ pooled, float* __restrict__ counts, int n) {
    int f = threadIdx.x & 63, g = threadIdx.x >> 6;
    int start = (blockIdx.x * 4 + g) * 64;
    if (start >= n) return;
    int end = min(start + 64, n);
    int cur = batch[start];
    float acc = 0.0f, cnt = 0.0f;
    for (int i = start; i < end; ++i) {
        int bg = batch[i];
        if (bg != cur) {
            atomicAdd(&pooled[cur * HID + f], acc);
            if (f == 0) atomicAdd(&counts[cur], cnt);
            acc = 0.0f; cnt = 0.0f; cur = bg;
        }
        acc += H[(size_t)i * HID + f];
        cnt += 1.0f;
    }
    atomicAdd(&pooled[cur * HID + f], acc);
    if (f == 0) atomicAdd(&counts[cur], cnt);
}

__global__ void finalize(const float* __restrict__ pooled, const float* __restrict__ counts,
                         float* __restrict__ out, int total) {
    int tid = blockIdx.x * blockDim.x + threadIdx.x;
    if (tid < total) {
        float c = counts[tid >> 6];
        out[tid] = pooled[tid] / fmaxf(c, 1.0f);
    }
}

// ---------------- launcher ----------------

extern "C" void kernel_launch(void* const* d_in, const int* in_sizes, int n_in,
                              void* d_out, int out_size, void* d_ws, size_t ws_size,
                              hipStream_t stream) {
    const float* x  = (const float*)d_in[0];
    const float* W1 = (const float*)d_in[1];
    const float* b1 = (const float*)d_in[2];
    const float* W2 = (const float*)d_in[3];
    const float* b2 = (const float*)d_in[4];
    const int*   ei = (const int*)d_in[5];
    const int*   batch = (const int*)d_in[6];

    const int n  = in_sizes[0] / 3;   // 100000
    const int nE = in_sizes[5] / 2;   // 1000000
    const int* src = ei;
    const int* dst = ei + nE;

    // workspace layout (all chunks 16B-aligned for these sizes)
    char* p = (char*)d_ws;
    int*   cnt     = (int*)p;                 p += (size_t)n * 4;
    int*   off     = (int*)p;                 p += (size_t)n * 4;
    int*   bsums   = (int*)p;                 p += 512 * 4;
    int*   csr_src = (int*)p;                 p += (size_t)nE * 4;
    float* dinv    = (float*)p;               p += (size_t)n * 4;
    float* A       = (float*)p;               p += (size_t)n * HID * 4;
    float* B       = (float*)p;               p += (size_t)n * HID * 4;
    float* pooled  = (float*)p;               p += N_GRAPHS_C * HID * 4;
    float* counts  = (float*)p;               p += N_GRAPHS_C * 4;

    const int BT = 256;
    const int gridNode = (n + BT - 1) / BT;          // 391
    const int gridEdge = (nE + BT - 1) / BT;
    const int gridNF   = (n * HID + BT - 1) / BT;
    const int gridWave = (n + 3) / 4;                // 4 waves/block, 1 node/wave
    const int gridMM2  = (n + MM2_NODES - 1) / MM2_NODES;
    const int gridFin  = (N_GRAPHS_C * HID + BT - 1) / BT;

    // CSR build + dinv
    hipMemsetAsync(cnt, 0, (size_t)n * 4, stream);
    count_deg<<<gridEdge, BT, 0, stream>>>(dst, cnt, nE);
    dinv_from_cnt<<<gridNode, BT, 0, stream>>>(cnt, dinv, n);
    scan1<<<gridNode, SCAN_BLK, 0, stream>>>(cnt, off, bsums, n);
    scan2<<<1, 512, 0, stream>>>(bsums, gridNode);
    add_off<<<gridNode, BT, 0, stream>>>(off, bsums, n);
    fill_csr<<<gridEdge, BT, 0, stream>>>(src, dst, off, csr_src, nE);

    // layer 1
    mm1<<<gridNF, BT, 0, stream>>>(x, W1, dinv, A, n);
    gather_nodes<<<gridWave, BT, 0, stream>>>(A, dinv, csr_src, off, cnt, b1, B, n);

    // layer 2
    mm2<<<gridMM2, BT, 0, stream>>>(B, W2, dinv, A, n);
    gather_nodes<<<gridWave, BT, 0, stream>>>(A, dinv, csr_src, off, cnt, b2, B, n);

    // pool
    hipMemsetAsync(pooled, 0, (size_t)(N_GRAPHS_C * HID + N_GRAPHS_C) * 4, stream);
    pool<<<gridNode, BT, 0, stream>>>(B, batch, pooled, counts, n);
    finalize<<<gridFin, BT, 0, stream>>>(pooled, counts, (float*)d_out, N_GRAPHS_C * HID);
}

// Round 3
// 420.040 us; speedup vs baseline: 4.3973x; 1.1136x over previous
//
#include <hip/hip_runtime.h>

#define HID 64
#define N_GRAPHS_C 512
#define SCAN_BLK 256

// ---------------- CSR build ----------------

__global__ void count_deg(const int* __restrict__ dst, int* __restrict__ cnt, int nE) {
    int e = blockIdx.x * blockDim.x + threadIdx.x;
    if (e < nE) atomicAdd(&cnt[dst[e]], 1);
}

// exclusive scan (256/block) + block sums; also emits dinv = rsqrt(deg+1)
__global__ void scan1(const int* __restrict__ cnt, int* __restrict__ off,
                      int* __restrict__ bsums, float* __restrict__ dinv, int n) {
    __shared__ int tmp[SCAN_BLK];
    int t = threadIdx.x;
    int i = blockIdx.x * SCAN_BLK + t;
    int v = (i < n) ? cnt[i] : 0;
    if (i < n) dinv[i] = rsqrtf((float)(v + 1));  // +1 self-loop
    tmp[t] = v;
    __syncthreads();
    for (int d = 1; d < SCAN_BLK; d <<= 1) {
        int add = (t >= d) ? tmp[t - d] : 0;
        __syncthreads();
        tmp[t] += add;
        __syncthreads();
    }
    if (i < n) off[i] = tmp[t] - v;  // exclusive
    if (t == SCAN_BLK - 1) bsums[blockIdx.x] = tmp[t];
}

// exclusive scan of block sums (nb <= 512), single block of 512
__global__ void scan2(int* __restrict__ bsums, int nb) {
    __shared__ int tmp[512];
    int t = threadIdx.x;
    int v = (t < nb) ? bsums[t] : 0;
    tmp[t] = v;
    __syncthreads();
    for (int d = 1; d < 512; d <<= 1) {
        int add = (t >= d) ? tmp[t - d] : 0;
        __syncthreads();
        tmp[t] += add;
        __syncthreads();
    }
    if (t < nb) bsums[t] = tmp[t] - v;
}

__global__ void add_off(int* __restrict__ off, const int* __restrict__ bsums, int n) {
    int i = blockIdx.x * blockDim.x + threadIdx.x;
    if (i < n) off[i] += bsums[i >> 8];  // SCAN_BLK == 256
}

// bin sources by dst; off[d] becomes bucket END afterwards
__global__ void fill_csr(const int* __restrict__ src, const int* __restrict__ dst,
                         int* __restrict__ off, int* __restrict__ csr_src, int nE) {
    int e = blockIdx.x * blockDim.x + threadIdx.x;
    if (e < nE) {
        int d = dst[e];
        int pos = atomicAdd(&off[d], 1);
        csr_src[pos] = src[e];
    }
}

// ---------------- layer 1 matmul: A = (x @ W1) * dinv[node] ----------------

__global__ void mm1(const float* __restrict__ x, const float* __restrict__ W1,
                    const float* __restrict__ dinv, float* __restrict__ A, int n) {
    __shared__ float w[3 * HID];
    int t = threadIdx.x;
    if (t < 3 * HID) w[t] = W1[t];
    __syncthreads();
    int tid = blockIdx.x * blockDim.x + t;
    int node = tid >> 6, f = tid & 63;
    if (node < n) {
        float x0 = x[node * 3 + 0], x1 = x[node * 3 + 1], x2 = x[node * 3 + 2];
        A[tid] = (x0 * w[f] + x1 * w[HID + f] + x2 * w[2 * HID + f]) * dinv[node];
    }
}

// ---------------- gather aggregation ----------------
// One wave per dst node; lane = feature. A pre-scaled by dinv[src].
// Unrolled x4: 4 independent row loads in flight per wave.

__global__ void gather_nodes(const float* __restrict__ A, const float* __restrict__ dinv,
                             const int* __restrict__ csr_src, const int* __restrict__ off_end,
                             const int* __restrict__ cnt, const float* __restrict__ bias,
                             float* __restrict__ H, int n) {
    int node = blockIdx.x * (blockDim.x >> 6) + (threadIdx.x >> 6);
    int f = threadIdx.x & 63;
    if (node >= n) return;
    int end = off_end[node];
    int beg = end - cnt[node];
    float acc = A[(size_t)node * HID + f];  // self-loop (already *dinv[node])
    int k = beg;
    for (; k + 4 <= end; k += 4) {
        int s0 = csr_src[k + 0];
        int s1 = csr_src[k + 1];
        int s2 = csr_src[k + 2];
        int s3 = csr_src[k + 3];
        float a0 = A[(size_t)s0 * HID + f];
        float a1 = A[(size_t)s1 * HID + f];
        float a2 = A[(size_t)s2 * HID + f];
        float a3 = A[(size_t)s3 * HID + f];
        acc += a0;
        acc += a1;
        acc += a2;
        acc += a3;
    }
    for (; k < end; ++k) {
        int s = csr_src[k];
        acc += A[(size_t)s * HID + f];
    }
    float v = acc * dinv[node] + bias[f];
    H[(size_t)node * HID + f] = v > 0.0f ? v : 0.0f;
}

// ---------------- layer 2 matmul: A = (H @ W2) * dinv[node] ----------------

#define MM2_NODES 16
__global__ void mm2(const float* __restrict__ H, const float* __restrict__ W2,
                    const float* __restrict__ dinv, float* __restrict__ A, int n) {
    __shared__ float w[HID * HID];        // 16 KB
    __shared__ float h[MM2_NODES * HID];  // 4 KB
    int t = threadIdx.x;  // 256
    for (int i = t; i < HID * HID; i += 256) w[i] = W2[i];
    int base = blockIdx.x * MM2_NODES;
    for (int i = t; i < MM2_NODES * HID; i += 256) {
        int node = base + (i >> 6);
        h[i] = (node < n) ? H[(size_t)node * HID + (i & 63)] : 0.0f;
    }
    __syncthreads();
    int f = t & 63, g = t >> 6;
    float acc0 = 0.f, acc1 = 0.f, acc2 = 0.f, acc3 = 0.f;
    #pragma unroll 8
    for (int k = 0; k < HID; ++k) {
        float wk = w[k * HID + f];
        acc0 += h[(g * 4 + 0) * HID + k] * wk;
        acc1 += h[(g * 4 + 1) * HID + k] * wk;
        acc2 += h[(g * 4 + 2) * HID + k] * wk;
        acc3 += h[(g * 4 + 3) * HID + k] * wk;
    }
    float accs[4] = {acc0, acc1, acc2, acc3};
    #pragma unroll
    for (int j = 0; j < 4; ++j) {
        int node = base + g * 4 + j;
        if (node < n) A[(size_t)node * HID + f] = accs[j] * dinv[node];
    }
}

// ---------------- global mean pool: one wave per graph (batch sorted) -------

__device__ __forceinline__ int lower_bound(const int* __restrict__ a, int n, int key) {
    int lo = 0, hi = n;
    while (lo < hi) {
        int mid = (lo + hi) >> 1;
        if (a[mid] < key) lo = mid + 1; else hi = mid;
    }
    return lo;
}

__global__ void pool2(const float* __restrict__ H, const int* __restrict__ batch,
                      float* __restrict__ out, int n) {
    int g = blockIdx.x * (blockDim.x >> 6) + (threadIdx.x >> 6);  // graph id
    int f = threadIdx.x & 63;
    if (g >= N_GRAPHS_C) return;
    int lo = lower_bound(batch, n, g);
    int hi = lower_bound(batch, n, g + 1);
    float acc = 0.0f;
    for (int i = lo; i < hi; ++i) acc += H[(size_t)i * HID + f];
    float c = (float)(hi - lo);
    out[(size_t)g * HID + f] = acc / fmaxf(c, 1.0f);
}

// ---------------- launcher ----------------

extern "C" void kernel_launch(void* const* d_in, const int* in_sizes, int n_in,
                              void* d_out, int out_size, void* d_ws, size_t ws_size,
                              hipStream_t stream) {
    const float* x  = (const float*)d_in[0];
    const float* W1 = (const float*)d_in[1];
    const float* b1 = (const float*)d_in[2];
    const float* W2 = (const float*)d_in[3];
    const float* b2 = (const float*)d_in[4];
    const int*   ei = (const int*)d_in[5];
    const int*   batch = (const int*)d_in[6];

    const int n  = in_sizes[0] / 3;   // 100000
    const int nE = in_sizes[5] / 2;   // 1000000
    const int* src = ei;
    const int* dst = ei + nE;

    char* p = (char*)d_ws;
    int*   cnt     = (int*)p;                 p += (size_t)n * 4;
    int*   off     = (int*)p;                 p += (size_t)n * 4;
    int*   bsums   = (int*)p;                 p += 512 * 4;
    int*   csr_src = (int*)p;                 p += (size_t)nE * 4;
    float* dinv    = (float*)p;               p += (size_t)n * 4;
    float* A       = (float*)p;               p += (size_t)n * HID * 4;
    float* B       = (float*)p;               p += (size_t)n * HID * 4;

    const int BT = 256;
    const int gridNode = (n + BT - 1) / BT;          // 391
    const int gridEdge = (nE + BT - 1) / BT;
    const int gridNF   = (n * HID + BT - 1) / BT;
    const int gridWave = (n + 3) / 4;                // 4 waves/block, 1 node/wave
    const int gridMM2  = (n + MM2_NODES - 1) / MM2_NODES;
    const int gridPool = (N_GRAPHS_C + 3) / 4;       // 4 graphs/block

    // CSR build + dinv
    hipMemsetAsync(cnt, 0, (size_t)n * 4, stream);
    count_deg<<<gridEdge, BT, 0, stream>>>(dst, cnt, nE);
    scan1<<<gridNode, SCAN_BLK, 0, stream>>>(cnt, off, bsums, dinv, n);
    scan2<<<1, 512, 0, stream>>>(bsums, gridNode);
    add_off<<<gridNode, BT, 0, stream>>>(off, bsums, n);
    fill_csr<<<gridEdge, BT, 0, stream>>>(src, dst, off, csr_src, nE);

    // layer 1
    mm1<<<gridNF, BT, 0, stream>>>(x, W1, dinv, A, n);
    gather_nodes<<<gridWave, BT, 0, stream>>>(A, dinv, csr_src, off, cnt, b1, B, n);

    // layer 2
    mm2<<<gridMM2, BT, 0, stream>>>(B, W2, dinv, A, n);
    gather_nodes<<<gridWave, BT, 0, stream>>>(A, dinv, csr_src, off, cnt, b2, B, n);

    // pool (no atomics: binary-search per-graph ranges over sorted batch)
    pool2<<<gridPool, BT, 0, stream>>>(B, batch, (float*)d_out, n);
}

// Round 4
// 375.470 us; speedup vs baseline: 4.9193x; 1.1187x over previous
//
#include <hip/hip_runtime.h>

#define HID 64
#define N_GRAPHS_C 512
#define SCAN_BLK 256

// ---------------- CSR build ----------------

__global__ void count_deg(const int* __restrict__ dst, int* __restrict__ cnt, int nE) {
    int e = blockIdx.x * blockDim.x + threadIdx.x;
    if (e < nE) atomicAdd(&cnt[dst[e]], 1);
}

// exclusive scan (256/block) + block sums; also emits dinv = rsqrt(deg+1)
__global__ void scan1(const int* __restrict__ cnt, int* __restrict__ off,
                      int* __restrict__ bsums, float* __restrict__ dinv, int n) {
    __shared__ int tmp[SCAN_BLK];
    int t = threadIdx.x;
    int i = blockIdx.x * SCAN_BLK + t;
    int v = (i < n) ? cnt[i] : 0;
    if (i < n) dinv[i] = rsqrtf((float)(v + 1));  // +1 self-loop
    tmp[t] = v;
    __syncthreads();
    for (int d = 1; d < SCAN_BLK; d <<= 1) {
        int add = (t >= d) ? tmp[t - d] : 0;
        __syncthreads();
        tmp[t] += add;
        __syncthreads();
    }
    if (i < n) off[i] = tmp[t] - v;  // exclusive
    if (t == SCAN_BLK - 1) bsums[blockIdx.x] = tmp[t];
}

__global__ void scan2(int* __restrict__ bsums, int nb) {
    __shared__ int tmp[512];
    int t = threadIdx.x;
    int v = (t < nb) ? bsums[t] : 0;
    tmp[t] = v;
    __syncthreads();
    for (int d = 1; d < 512; d <<= 1) {
        int add = (t >= d) ? tmp[t - d] : 0;
        __syncthreads();
        tmp[t] += add;
        __syncthreads();
    }
    if (t < nb) bsums[t] = tmp[t] - v;
}

__global__ void add_off(int* __restrict__ off, const int* __restrict__ bsums, int n) {
    int i = blockIdx.x * blockDim.x + threadIdx.x;
    if (i < n) off[i] += bsums[i >> 8];  // SCAN_BLK == 256
}

// bin sources by dst; off[d] becomes bucket END afterwards
__global__ void fill_csr(const int* __restrict__ src, const int* __restrict__ dst,
                         int* __restrict__ off, int* __restrict__ csr_src, int nE) {
    int e = blockIdx.x * blockDim.x + threadIdx.x;
    if (e < nE) {
        int d = dst[e];
        int pos = atomicAdd(&off[d], 1);
        csr_src[pos] = src[e];
    }
}

// ---------------- layer 1 matmul: A = (x @ W1) * dinv[node] ----------------

__global__ void mm1(const float* __restrict__ x, const float* __restrict__ W1,
                    const float* __restrict__ dinv, float* __restrict__ A, int n) {
    __shared__ float w[3 * HID];
    int t = threadIdx.x;
    if (t < 3 * HID) w[t] = W1[t];
    __syncthreads();
    int tid = blockIdx.x * blockDim.x + t;
    int node = tid >> 6, f = tid & 63;
    if (node < n) {
        float x0 = x[node * 3 + 0], x1 = x[node * 3 + 1], x2 = x[node * 3 + 2];
        A[tid] = (x0 * w[f] + x1 * w[HID + f] + x2 * w[2 * HID + f]) * dinv[node];
    }
}

// ---------------- gather aggregation ----------------
// One wave per dst node; lane = feature. A pre-scaled by dinv[src].
// Bucket of node d is [off_end[d-1], off_end[d]) — contiguous buckets.
// Unrolled x8 for memory-level parallelism.

__global__ void gather_nodes(const float* __restrict__ A, const float* __restrict__ dinv,
                             const int* __restrict__ csr_src, const int* __restrict__ off_end,
                             const float* __restrict__ bias,
                             float* __restrict__ H, int n) {
    int node = blockIdx.x * (blockDim.x >> 6) + (threadIdx.x >> 6);
    int f = threadIdx.x & 63;
    if (node >= n) return;
    int end = off_end[node];
    int beg = (node == 0) ? 0 : off_end[node - 1];
    float acc = A[(size_t)node * HID + f];  // self-loop (already *dinv[node])
    int k = beg;
    for (; k + 8 <= end; k += 8) {
        int s0 = csr_src[k + 0];
        int s1 = csr_src[k + 1];
        int s2 = csr_src[k + 2];
        int s3 = csr_src[k + 3];
        int s4 = csr_src[k + 4];
        int s5 = csr_src[k + 5];
        int s6 = csr_src[k + 6];
        int s7 = csr_src[k + 7];
        float a0 = A[(size_t)s0 * HID + f];
        float a1 = A[(size_t)s1 * HID + f];
        float a2 = A[(size_t)s2 * HID + f];
        float a3 = A[(size_t)s3 * HID + f];
        float a4 = A[(size_t)s4 * HID + f];
        float a5 = A[(size_t)s5 * HID + f];
        float a6 = A[(size_t)s6 * HID + f];
        float a7 = A[(size_t)s7 * HID + f];
        acc += a0; acc += a1; acc += a2; acc += a3;
        acc += a4; acc += a5; acc += a6; acc += a7;
    }
    for (; k < end; ++k) {
        int s = csr_src[k];
        acc += A[(size_t)s * HID + f];
    }
    float v = acc * dinv[node] + bias[f];
    H[(size_t)node * HID + f] = v > 0.0f ? v : 0.0f;
}

// ---------------- layer 2 matmul: A = (H @ W2) * dinv[node] ----------------

#define MM2_NODES 16
__global__ void mm2(const float* __restrict__ H, const float* __restrict__ W2,
                    const float* __restrict__ dinv, float* __restrict__ A, int n) {
    __shared__ float w[HID * HID];        // 16 KB
    __shared__ float h[MM2_NODES * HID];  // 4 KB
    int t = threadIdx.x;  // 256
    for (int i = t; i < HID * HID; i += 256) w[i] = W2[i];
    int base = blockIdx.x * MM2_NODES;
    for (int i = t; i < MM2_NODES * HID; i += 256) {
        int node = base + (i >> 6);
        h[i] = (node < n) ? H[(size_t)node * HID + (i & 63)] : 0.0f;
    }
    __syncthreads();
    int f = t & 63, g = t >> 6;
    float acc0 = 0.f, acc1 = 0.f, acc2 = 0.f, acc3 = 0.f;
    #pragma unroll 8
    for (int k = 0; k < HID; ++k) {
        float wk = w[k * HID + f];
        acc0 += h[(g * 4 + 0) * HID + k] * wk;
        acc1 += h[(g * 4 + 1) * HID + k] * wk;
        acc2 += h[(g * 4 + 2) * HID + k] * wk;
        acc3 += h[(g * 4 + 3) * HID + k] * wk;
    }
    float accs[4] = {acc0, acc1, acc2, acc3};
    #pragma unroll
    for (int j = 0; j < 4; ++j) {
        int node = base + g * 4 + j;
        if (node < n) A[(size_t)node * HID + f] = accs[j] * dinv[node];
    }
}

// ---------------- global mean pool (batch sorted): chunked, boundary-flush --

__global__ void pool(const float* __restrict__ H, const int* __restrict__ batch,
                     float* __restrict__ pooled, float* __restrict__ counts, int n) {
    int f = threadIdx.x & 63, g = threadIdx.x >> 6;
    int start = (blockIdx.x * 4 + g) * 64;
    if (start >= n) return;
    int end = min(start + 64, n);
    int cur = batch[start];
    float acc = 0.0f, cnt = 0.0f;
    for (int i = start; i < end; ++i) {
        int bg = batch[i];
        if (bg != cur) {
            atomicAdd(&pooled[cur * HID + f], acc);
            if (f == 0) atomicAdd(&counts[cur], cnt);
            acc = 0.0f; cnt = 0.0f; cur = bg;
        }
        acc += H[(size_t)i * HID + f];
        cnt += 1.0f;
    }
    atomicAdd(&pooled[cur * HID + f], acc);
    if (f == 0) atomicAdd(&counts[cur], cnt);
}

__global__ void finalize(const float* __restrict__ pooled, const float* __restrict__ counts,
                         float* __restrict__ out, int total) {
    int tid = blockIdx.x * blockDim.x + threadIdx.x;
    if (tid < total) {
        float c = counts[tid >> 6];
        out[tid] = pooled[tid] / fmaxf(c, 1.0f);
    }
}

// ---------------- launcher ----------------

extern "C" void kernel_launch(void* const* d_in, const int* in_sizes, int n_in,
                              void* d_out, int out_size, void* d_ws, size_t ws_size,
                              hipStream_t stream) {
    const float* x  = (const float*)d_in[0];
    const float* W1 = (const float*)d_in[1];
    const float* b1 = (const float*)d_in[2];
    const float* W2 = (const float*)d_in[3];
    const float* b2 = (const float*)d_in[4];
    const int*   ei = (const int*)d_in[5];
    const int*   batch = (const int*)d_in[6];

    const int n  = in_sizes[0] / 3;   // 100000
    const int nE = in_sizes[5] / 2;   // 1000000
    const int* src = ei;
    const int* dst = ei + nE;

    char* p = (char*)d_ws;
    int*   cnt     = (int*)p;                 p += (size_t)n * 4;
    int*   off     = (int*)p;                 p += (size_t)n * 4;
    int*   bsums   = (int*)p;                 p += 512 * 4;
    int*   csr_src = (int*)p;                 p += (size_t)nE * 4;
    float* dinv    = (float*)p;               p += (size_t)n * 4;
    float* A       = (float*)p;               p += (size_t)n * HID * 4;
    float* B       = (float*)p;               p += (size_t)n * HID * 4;
    float* pooled  = (float*)p;               p += N_GRAPHS_C * HID * 4;
    float* counts  = (float*)p;               p += N_GRAPHS_C * 4;

    const int BT = 256;
    const int gridNode = (n + BT - 1) / BT;          // 391
    const int gridEdge = (nE + BT - 1) / BT;
    const int gridNF   = (n * HID + BT - 1) / BT;
    const int gridWave = (n + 3) / 4;                // 4 waves/block, 1 node/wave
    const int gridMM2  = (n + MM2_NODES - 1) / MM2_NODES;
    const int gridFin  = (N_GRAPHS_C * HID + BT - 1) / BT;

    // CSR build + dinv
    hipMemsetAsync(cnt, 0, (size_t)n * 4, stream);
    count_deg<<<gridEdge, BT, 0, stream>>>(dst, cnt, nE);
    scan1<<<gridNode, SCAN_BLK, 0, stream>>>(cnt, off, bsums, dinv, n);
    scan2<<<1, 512, 0, stream>>>(bsums, gridNode);
    add_off<<<gridNode, BT, 0, stream>>>(off, bsums, n);
    fill_csr<<<gridEdge, BT, 0, stream>>>(src, dst, off, csr_src, nE);

    // layer 1
    mm1<<<gridNF, BT, 0, stream>>>(x, W1, dinv, A, n);
    gather_nodes<<<gridWave, BT, 0, stream>>>(A, dinv, csr_src, off, b1, B, n);

    // layer 2
    mm2<<<gridMM2, BT, 0, stream>>>(B, W2, dinv, A, n);
    gather_nodes<<<gridWave, BT, 0, stream>>>(A, dinv, csr_src, off, b2, B, n);

    // pool: chunked accumulation (1563 waves) + finalize
    hipMemsetAsync(pooled, 0, (size_t)(N_GRAPHS_C * HID + N_GRAPHS_C) * 4, stream);
    pool<<<gridNode, BT, 0, stream>>>(B, batch, pooled, counts, n);
    finalize<<<gridFin, BT, 0, stream>>>(pooled, counts, (float*)d_out, N_GRAPHS_C * HID);
}

// Round 5
// 304.309 us; speedup vs baseline: 6.0697x; 1.2338x over previous
//
#include <hip/hip_runtime.h>

#define HID 64
#define N_GRAPHS_C 512
#define BSHIFT 9          // 512 nodes per coarse bucket
#define EPB 4096          // edges per block in hist/bin passes

// ---------------- CSR build: two-level counting sort ----------------

// Pass A: coarse histogram (bucket = dst >> BSHIFT)
__global__ void coarse_hist(const int* __restrict__ dst, int* __restrict__ ghist,
                            int nE, int nbuck) {
    __shared__ int lh[256];
    int t = threadIdx.x;
    lh[t] = 0;
    __syncthreads();
    int base = blockIdx.x * EPB;
    #pragma unroll
    for (int j = 0; j < 16; ++j) {
        int e = base + j * 256 + t;
        if (e < nE) atomicAdd(&lh[dst[e] >> BSHIFT], 1);
    }
    __syncthreads();
    if (t < nbuck && lh[t] > 0) atomicAdd(&ghist[t], lh[t]);
}

// Pass A2: exclusive scan of bucket sizes (nbuck <= 255); also zeros cursors
__global__ void scan_buckets(const int* __restrict__ ghist, int* __restrict__ bbase,
                             int* __restrict__ gcursor, int nbuck) {
    __shared__ int tmp[256];
    int t = threadIdx.x;
    int v = (t < nbuck) ? ghist[t] : 0;
    tmp[t] = v;
    __syncthreads();
    for (int d = 1; d < 256; d <<= 1) {
        int add = (t >= d) ? tmp[t - d] : 0;
        __syncthreads();
        tmp[t] += add;
        __syncthreads();
    }
    if (t <= nbuck) bbase[t] = tmp[t] - v;   // exclusive; bbase[nbuck] = nE
    if (t < nbuck) gcursor[t] = 0;
}

// Pass B: scatter (src,dst) pairs into coarse-bucket regions.
// Per-block LDS histogram + one global reservation atomic per bucket.
__global__ void bin_pairs(const int* __restrict__ src, const int* __restrict__ dst,
                          const int* __restrict__ bbase, int* __restrict__ gcursor,
                          int2* __restrict__ pairs, int nE, int nbuck) {
    __shared__ int lh[256];
    __shared__ int lbase[256];
    int t = threadIdx.x;
    lh[t] = 0;
    __syncthreads();
    int base = blockIdx.x * EPB;
    int sj[16], dj[16], rj[16], bj[16];
    #pragma unroll
    for (int j = 0; j < 16; ++j) {
        int e = base + j * 256 + t;
        if (e < nE) {
            sj[j] = src[e];
            dj[j] = dst[e];
            bj[j] = dj[j] >> BSHIFT;
            rj[j] = atomicAdd(&lh[bj[j]], 1);
        } else {
            bj[j] = -1;
        }
    }
    __syncthreads();
    if (t < nbuck) lbase[t] = (lh[t] > 0) ? atomicAdd(&gcursor[t], lh[t]) : 0;
    __syncthreads();
    #pragma unroll
    for (int j = 0; j < 16; ++j) {
        if (bj[j] >= 0) {
            int pos = bbase[bj[j]] + lbase[bj[j]] + rj[j];
            pairs[pos] = make_int2(sj[j], dj[j]);
        }
    }
}

// Pass C: one block per coarse bucket. LDS histogram over 512 local nodes,
// LDS scan -> off_end + dinv, then LDS-cursor fill of csr_src (writes stay
// inside a ~20KB L2-resident window).
__global__ void build_csr(const int2* __restrict__ pairs, const int* __restrict__ bbase,
                          int* __restrict__ csr_src, int* __restrict__ off_end,
                          float* __restrict__ dinv, int n) {
    __shared__ int hist[512];
    __shared__ int tmp[256];
    int t = threadIdx.x;
    int b = blockIdx.x;
    int pbeg = bbase[b], pend = bbase[b + 1];
    hist[t] = 0; hist[t + 256] = 0;
    __syncthreads();
    int nbeg = b << BSHIFT;
    for (int i = pbeg + t; i < pend; i += 256)
        atomicAdd(&hist[pairs[i].y - nbeg], 1);
    __syncthreads();
    int v0 = hist[2 * t], v1 = hist[2 * t + 1];
    int ps = v0 + v1;
    tmp[t] = ps;
    __syncthreads();
    for (int d = 1; d < 256; d <<= 1) {
        int add = (t >= d) ? tmp[t - d] : 0;
        __syncthreads();
        tmp[t] += add;
        __syncthreads();
    }
    int pexcl = tmp[t] - ps;          // exclusive scan of pair-sums
    int e0 = pexcl, e1 = pexcl + v0;  // exclusive scan per node
    int n0 = nbeg + 2 * t, n1 = n0 + 1;
    if (n0 < n) { off_end[n0] = pbeg + e0 + v0; dinv[n0] = rsqrtf((float)(v0 + 1)); }
    if (n1 < n) { off_end[n1] = pbeg + e1 + v1; dinv[n1] = rsqrtf((float)(v1 + 1)); }
    hist[2 * t]     = pbeg + e0;      // repurpose hist as fill cursors
    hist[2 * t + 1] = pbeg + e1;
    __syncthreads();
    for (int i = pbeg + t; i < pend; i += 256) {
        int2 p = pairs[i];
        int pos = atomicAdd(&hist[p.y - nbeg], 1);
        csr_src[pos] = p.x;
    }
}

// ---------------- layer 1 matmul: A = (x @ W1) * dinv[node] ----------------

__global__ void mm1(const float* __restrict__ x, const float* __restrict__ W1,
                    const float* __restrict__ dinv, float* __restrict__ A, int n) {
    __shared__ float w[3 * HID];
    int t = threadIdx.x;
    if (t < 3 * HID) w[t] = W1[t];
    __syncthreads();
    int tid = blockIdx.x * blockDim.x + t;
    int node = tid >> 6, f = tid & 63;
    if (node < n) {
        float x0 = x[node * 3 + 0], x1 = x[node * 3 + 1], x2 = x[node * 3 + 2];
        A[tid] = (x0 * w[f] + x1 * w[HID + f] + x2 * w[2 * HID + f]) * dinv[node];
    }
}

// ---------------- gather aggregation ----------------

__global__ void gather_nodes(const float* __restrict__ A, const float* __restrict__ dinv,
                             const int* __restrict__ csr_src, const int* __restrict__ off_end,
                             const float* __restrict__ bias,
                             float* __restrict__ H, int n) {
    int node = blockIdx.x * (blockDim.x >> 6) + (threadIdx.x >> 6);
    int f = threadIdx.x & 63;
    if (node >= n) return;
    int end = off_end[node];
    int beg = (node == 0) ? 0 : off_end[node - 1];
    float acc = A[(size_t)node * HID + f];  // self-loop (already *dinv[node])
    int k = beg;
    for (; k + 8 <= end; k += 8) {
        int s0 = csr_src[k + 0];
        int s1 = csr_src[k + 1];
        int s2 = csr_src[k + 2];
        int s3 = csr_src[k + 3];
        int s4 = csr_src[k + 4];
        int s5 = csr_src[k + 5];
        int s6 = csr_src[k + 6];
        int s7 = csr_src[k + 7];
        float a0 = A[(size_t)s0 * HID + f];
        float a1 = A[(size_t)s1 * HID + f];
        float a2 = A[(size_t)s2 * HID + f];
        float a3 = A[(size_t)s3 * HID + f];
        float a4 = A[(size_t)s4 * HID + f];
        float a5 = A[(size_t)s5 * HID + f];
        float a6 = A[(size_t)s6 * HID + f];
        float a7 = A[(size_t)s7 * HID + f];
        acc += a0; acc += a1; acc += a2; acc += a3;
        acc += a4; acc += a5; acc += a6; acc += a7;
    }
    for (; k < end; ++k) {
        int s = csr_src[k];
        acc += A[(size_t)s * HID + f];
    }
    float v = acc * dinv[node] + bias[f];
    H[(size_t)node * HID + f] = v > 0.0f ? v : 0.0f;
}

// ---------------- layer 2 matmul: A = (H @ W2) * dinv[node] ----------------

#define MM2_NODES 16
__global__ void mm2(const float* __restrict__ H, const float* __restrict__ W2,
                    const float* __restrict__ dinv, float* __restrict__ A, int n) {
    __shared__ float w[HID * HID];
    __shared__ float h[MM2_NODES * HID];
    int t = threadIdx.x;
    for (int i = t; i < HID * HID; i += 256) w[i] = W2[i];
    int base = blockIdx.x * MM2_NODES;
    for (int i = t; i < MM2_NODES * HID; i += 256) {
        int node = base + (i >> 6);
        h[i] = (node < n) ? H[(size_t)node * HID + (i & 63)] : 0.0f;
    }
    __syncthreads();
    int f = t & 63, g = t >> 6;
    float acc0 = 0.f, acc1 = 0.f, acc2 = 0.f, acc3 = 0.f;
    #pragma unroll 8
    for (int k = 0; k < HID; ++k) {
        float wk = w[k * HID + f];
        acc0 += h[(g * 4 + 0) * HID + k] * wk;
        acc1 += h[(g * 4 + 1) * HID + k] * wk;
        acc2 += h[(g * 4 + 2) * HID + k] * wk;
        acc3 += h[(g * 4 + 3) * HID + k] * wk;
    }
    float accs[4] = {acc0, acc1, acc2, acc3};
    #pragma unroll
    for (int j = 0; j < 4; ++j) {
        int node = base + g * 4 + j;
        if (node < n) A[(size_t)node * HID + f] = accs[j] * dinv[node];
    }
}

// ---------------- global mean pool (batch sorted): chunked, boundary-flush --

__global__ void pool(const float* __restrict__ H, const int* __restrict__ batch,
                     float* __restrict__ pooled, float* __restrict__ counts, int n) {
    int f = threadIdx.x & 63, g = threadIdx.x >> 6;
    int start = (blockIdx.x * 4 + g) * 64;
    if (start >= n) return;
    int end = min(start + 64, n);
    int cur = batch[start];
    float acc = 0.0f, cnt = 0.0f;
    for (int i = start; i < end; ++i) {
        int bg = batch[i];
        if (bg != cur) {
            atomicAdd(&pooled[cur * HID + f], acc);
            if (f == 0) atomicAdd(&counts[cur], cnt);
            acc = 0.0f; cnt = 0.0f; cur = bg;
        }
        acc += H[(size_t)i * HID + f];
        cnt += 1.0f;
    }
    atomicAdd(&pooled[cur * HID + f], acc);
    if (f == 0) atomicAdd(&counts[cur], cnt);
}

__global__ void finalize(const float* __restrict__ pooled, const float* __restrict__ counts,
                         float* __restrict__ out, int total) {
    int tid = blockIdx.x * blockDim.x + threadIdx.x;
    if (tid < total) {
        float c = counts[tid >> 6];
        out[tid] = pooled[tid] / fmaxf(c, 1.0f);
    }
}

// ---------------- launcher ----------------

extern "C" void kernel_launch(void* const* d_in, const int* in_sizes, int n_in,
                              void* d_out, int out_size, void* d_ws, size_t ws_size,
                              hipStream_t stream) {
    const float* x  = (const float*)d_in[0];
    const float* W1 = (const float*)d_in[1];
    const float* b1 = (const float*)d_in[2];
    const float* W2 = (const float*)d_in[3];
    const float* b2 = (const float*)d_in[4];
    const int*   ei = (const int*)d_in[5];
    const int*   batch = (const int*)d_in[6];

    const int n  = in_sizes[0] / 3;   // 100000
    const int nE = in_sizes[5] / 2;   // 1000000
    const int* src = ei;
    const int* dst = ei + nE;
    const int nbuck = (n + ((1 << BSHIFT) - 1)) >> BSHIFT;   // 196

    // workspace layout
    char* p = (char*)d_ws;
    int*   ghist   = (int*)p;                 // 256 ints
    int*   bbase   = ghist + 256;             // 257 ints
    int*   gcursor = bbase + 260;             // 256 ints
    p += 4096;
    int*   off     = (int*)p;                 p += (size_t)n * 4;
    float* dinv    = (float*)p;               p += (size_t)n * 4;
    int*   csr_src = (int*)p;                 p += (size_t)nE * 4;
    float* A       = (float*)p;               p += (size_t)n * HID * 4;
    float* B       = (float*)p;               p += (size_t)n * HID * 4;
    float* pooled  = (float*)p;               p += N_GRAPHS_C * HID * 4;
    float* counts  = (float*)p;               p += N_GRAPHS_C * 4;
    int2*  pairs   = (int2*)A;                // aliased: consumed before mm1 writes A

    const int BT = 256;
    const int gridNode = (n + BT - 1) / BT;
    const int gridE2   = (nE + EPB - 1) / EPB;           // 245
    const int gridNF   = (n * HID + BT - 1) / BT;
    const int gridWave = (n + 3) / 4;
    const int gridMM2  = (n + MM2_NODES - 1) / MM2_NODES;
    const int gridFin  = (N_GRAPHS_C * HID + BT - 1) / BT;

    // CSR build (two-level counting sort) + dinv
    hipMemsetAsync(ghist, 0, 256 * 4, stream);
    coarse_hist<<<gridE2, BT, 0, stream>>>(dst, ghist, nE, nbuck);
    scan_buckets<<<1, BT, 0, stream>>>(ghist, bbase, gcursor, nbuck);
    bin_pairs<<<gridE2, BT, 0, stream>>>(src, dst, bbase, gcursor, pairs, nE, nbuck);
    build_csr<<<nbuck, BT, 0, stream>>>(pairs, bbase, csr_src, off, dinv, n);

    // layer 1
    mm1<<<gridNF, BT, 0, stream>>>(x, W1, dinv, A, n);
    gather_nodes<<<gridWave, BT, 0, stream>>>(A, dinv, csr_src, off, b1, B, n);

    // layer 2
    mm2<<<gridMM2, BT, 0, stream>>>(B, W2, dinv, A, n);
    gather_nodes<<<gridWave, BT, 0, stream>>>(A, dinv, csr_src, off, b2, B, n);

    // pool
    hipMemsetAsync(pooled, 0, (size_t)(N_GRAPHS_C * HID + N_GRAPHS_C) * 4, stream);
    pool<<<gridNode, BT, 0, stream>>>(B, batch, pooled, counts, n);
    finalize<<<gridFin, BT, 0, stream>>>(pooled, counts, (float*)d_out, N_GRAPHS_C * HID);
}

// Round 6
// 288.557 us; speedup vs baseline: 6.4010x; 1.0546x over previous
//
#include <hip/hip_runtime.h>

#define HID 64
#define N_GRAPHS_C 512
#define BSHIFT 9          // 512 nodes per coarse bucket
#define CAP 6144          // bucket capacity (mean 5120 + 14 sigma)
#define EPB 4096          // edges per block in bin pass

typedef unsigned short u16;
typedef unsigned int u32;

__device__ __forceinline__ float bf2f(u16 u) {
    union { u32 i; float f; } v; v.i = ((u32)u) << 16; return v.f;
}
__device__ __forceinline__ u16 f2bf(float f) {
    union { float f; u32 i; } v; v.f = f;
    u32 x = v.i;
    return (u16)((x + 0x7fffu + ((x >> 16) & 1u)) >> 16);  // RNE
}

// ---------------- CSR build: single-pass binning, fixed-capacity buckets ----

__global__ void bin_pairs(const int* __restrict__ src, const int* __restrict__ dst,
                          int* __restrict__ gcursor, int2* __restrict__ pairs,
                          int nE, int nbuck) {
    __shared__ int lh[256];
    __shared__ int lbase[256];
    int t = threadIdx.x;
    lh[t] = 0;
    __syncthreads();
    int base = blockIdx.x * EPB;
    int sj[16], dj[16], rj[16], bj[16];
    #pragma unroll
    for (int j = 0; j < 16; ++j) {
        int e = base + j * 256 + t;
        if (e < nE) {
            sj[j] = src[e];
            dj[j] = dst[e];
            bj[j] = dj[j] >> BSHIFT;
            rj[j] = atomicAdd(&lh[bj[j]], 1);
        } else {
            bj[j] = -1;
        }
    }
    __syncthreads();
    if (t < nbuck) lbase[t] = (lh[t] > 0) ? atomicAdd(&gcursor[t], lh[t]) : 0;
    __syncthreads();
    #pragma unroll
    for (int j = 0; j < 16; ++j) {
        if (bj[j] >= 0) {
            int pos = bj[j] * CAP + lbase[bj[j]] + rj[j];
            pairs[pos] = make_int2(sj[j], dj[j]);
        }
    }
}

// One block per bucket: LDS histogram over 512 local nodes, LDS scan ->
// per-node (beg,end) + dinv, then LDS-cursor fill of csr_src.
__global__ void build_csr(const int2* __restrict__ pairs, const int* __restrict__ gcursor,
                          int* __restrict__ csr_src, int2* __restrict__ off2,
                          float* __restrict__ dinv, int n) {
    __shared__ int hist[512];
    __shared__ int tmp[256];
    int t = threadIdx.x;
    int b = blockIdx.x;
    int pbeg = b * CAP;
    int pend = pbeg + gcursor[b];
    hist[t] = 0; hist[t + 256] = 0;
    __syncthreads();
    int nbeg = b << BSHIFT;
    for (int i = pbeg + t; i < pend; i += 256)
        atomicAdd(&hist[pairs[i].y - nbeg], 1);
    __syncthreads();
    int v0 = hist[2 * t], v1 = hist[2 * t + 1];
    int ps = v0 + v1;
    tmp[t] = ps;
    __syncthreads();
    for (int d = 1; d < 256; d <<= 1) {
        int add = (t >= d) ? tmp[t - d] : 0;
        __syncthreads();
        tmp[t] += add;
        __syncthreads();
    }
    int pexcl = tmp[t] - ps;
    int e0 = pbeg + pexcl, e1 = e0 + v0;
    int n0 = nbeg + 2 * t, n1 = n0 + 1;
    if (n0 < n) { off2[n0] = make_int2(e0, e0 + v0); dinv[n0] = rsqrtf((float)(v0 + 1)); }
    if (n1 < n) { off2[n1] = make_int2(e1, e1 + v1); dinv[n1] = rsqrtf((float)(v1 + 1)); }
    hist[2 * t]     = e0;      // repurpose as fill cursors
    hist[2 * t + 1] = e1;
    __syncthreads();
    for (int i = pbeg + t; i < pend; i += 256) {
        int2 p = pairs[i];
        int pos = atomicAdd(&hist[p.y - nbeg], 1);
        csr_src[pos] = p.x;
    }
}

// ---------------- layer 1 matmul: A16 = bf16((x @ W1) * dinv) ----------------

__global__ void mm1(const float* __restrict__ x, const float* __restrict__ W1,
                    const float* __restrict__ dinv, u16* __restrict__ A16, int n) {
    __shared__ float w[3 * HID];
    int t = threadIdx.x;
    if (t < 3 * HID) w[t] = W1[t];
    __syncthreads();
    int tid = blockIdx.x * blockDim.x + t;
    int node = tid >> 6, f = tid & 63;
    if (node < n) {
        float x0 = x[node * 3 + 0], x1 = x[node * 3 + 1], x2 = x[node * 3 + 2];
        A16[tid] = f2bf((x0 * w[f] + x1 * w[HID + f] + x2 * w[2 * HID + f]) * dinv[node]);
    }
}

// ---------------- gather aggregation (bf16 rows) ----------------

__global__ void gather_nodes(const u16* __restrict__ A16, const float* __restrict__ dinv,
                             const int* __restrict__ csr_src, const int2* __restrict__ off2,
                             const float* __restrict__ bias,
                             u16* __restrict__ H16, int n) {
    int node = blockIdx.x * (blockDim.x >> 6) + (threadIdx.x >> 6);
    int f = threadIdx.x & 63;
    if (node >= n) return;
    int2 be = off2[node];
    int beg = be.x, end = be.y;
    float acc = bf2f(A16[(size_t)node * HID + f]);  // self-loop (already *dinv[node])
    int k = beg;
    for (; k + 8 <= end; k += 8) {
        int s0 = csr_src[k + 0];
        int s1 = csr_src[k + 1];
        int s2 = csr_src[k + 2];
        int s3 = csr_src[k + 3];
        int s4 = csr_src[k + 4];
        int s5 = csr_src[k + 5];
        int s6 = csr_src[k + 6];
        int s7 = csr_src[k + 7];
        u16 a0 = A16[(size_t)s0 * HID + f];
        u16 a1 = A16[(size_t)s1 * HID + f];
        u16 a2 = A16[(size_t)s2 * HID + f];
        u16 a3 = A16[(size_t)s3 * HID + f];
        u16 a4 = A16[(size_t)s4 * HID + f];
        u16 a5 = A16[(size_t)s5 * HID + f];
        u16 a6 = A16[(size_t)s6 * HID + f];
        u16 a7 = A16[(size_t)s7 * HID + f];
        acc += bf2f(a0); acc += bf2f(a1); acc += bf2f(a2); acc += bf2f(a3);
        acc += bf2f(a4); acc += bf2f(a5); acc += bf2f(a6); acc += bf2f(a7);
    }
    for (; k < end; ++k) {
        int s = csr_src[k];
        acc += bf2f(A16[(size_t)s * HID + f]);
    }
    float v = acc * dinv[node] + bias[f];
    H16[(size_t)node * HID + f] = f2bf(v > 0.0f ? v : 0.0f);
}

// ---------------- layer 2 matmul: A16 = bf16((H @ W2) * dinv) ----------------

#define MM2_NODES 16
__global__ void mm2(const u16* __restrict__ H16, const float* __restrict__ W2,
                    const float* __restrict__ dinv, u16* __restrict__ A16, int n) {
    __shared__ float w[HID * HID];
    __shared__ float h[MM2_NODES * HID];
    int t = threadIdx.x;
    for (int i = t; i < HID * HID; i += 256) w[i] = W2[i];
    int base = blockIdx.x * MM2_NODES;
    for (int i = t; i < MM2_NODES * HID; i += 256) {
        int node = base + (i >> 6);
        h[i] = (node < n) ? bf2f(H16[(size_t)node * HID + (i & 63)]) : 0.0f;
    }
    __syncthreads();
    int f = t & 63, g = t >> 6;
    float acc0 = 0.f, acc1 = 0.f, acc2 = 0.f, acc3 = 0.f;
    #pragma unroll 8
    for (int k = 0; k < HID; ++k) {
        float wk = w[k * HID + f];
        acc0 += h[(g * 4 + 0) * HID + k] * wk;
        acc1 += h[(g * 4 + 1) * HID + k] * wk;
        acc2 += h[(g * 4 + 2) * HID + k] * wk;
        acc3 += h[(g * 4 + 3) * HID + k] * wk;
    }
    float accs[4] = {acc0, acc1, acc2, acc3};
    #pragma unroll
    for (int j = 0; j < 4; ++j) {
        int node = base + g * 4 + j;
        if (node < n) A16[(size_t)node * HID + f] = f2bf(accs[j] * dinv[node]);
    }
}

// ---------------- global mean pool (batch sorted): chunked, boundary-flush --

__global__ void pool(const u16* __restrict__ H16, const int* __restrict__ batch,
                     float* __restrict__ pooled, float* __restrict__ counts, int n) {
    int f = threadIdx.x & 63, g = threadIdx.x >> 6;
    int start = (blockIdx.x * 4 + g) * 64;
    if (start >= n) return;
    int end = min(start + 64, n);
    int cur = batch[start];
    float acc = 0.0f, cnt = 0.0f;
    for (int i = start; i < end; ++i) {
        int bg = batch[i];
        if (bg != cur) {
            atomicAdd(&pooled[cur * HID + f], acc);
            if (f == 0) atomicAdd(&counts[cur], cnt);
            acc = 0.0f; cnt = 0.0f; cur = bg;
        }
        acc += bf2f(H16[(size_t)i * HID + f]);
        cnt += 1.0f;
    }
    atomicAdd(&pooled[cur * HID + f], acc);
    if (f == 0) atomicAdd(&counts[cur], cnt);
}

__global__ void finalize(const float* __restrict__ pooled, const float* __restrict__ counts,
                         float* __restrict__ out, int total) {
    int tid = blockIdx.x * blockDim.x + threadIdx.x;
    if (tid < total) {
        float c = counts[tid >> 6];
        out[tid] = pooled[tid] / fmaxf(c, 1.0f);
    }
}

// ---------------- launcher ----------------

extern "C" void kernel_launch(void* const* d_in, const int* in_sizes, int n_in,
                              void* d_out, int out_size, void* d_ws, size_t ws_size,
                              hipStream_t stream) {
    const float* x  = (const float*)d_in[0];
    const float* W1 = (const float*)d_in[1];
    const float* b1 = (const float*)d_in[2];
    const float* W2 = (const float*)d_in[3];
    const float* b2 = (const float*)d_in[4];
    const int*   ei = (const int*)d_in[5];
    const int*   batch = (const int*)d_in[6];

    const int n  = in_sizes[0] / 3;   // 100000
    const int nE = in_sizes[5] / 2;   // 1000000
    const int* src = ei;
    const int* dst = ei + nE;
    const int nbuck = (n + ((1 << BSHIFT) - 1)) >> BSHIFT;   // 196

    // workspace layout
    char* p = (char*)d_ws;
    int*   gcursor = (int*)p;                 p += 1024;
    int*   csr_src = (int*)p;                 p += (size_t)nbuck * CAP * 4;   // 4.8 MB
    int2*  off2    = (int2*)p;                p += (size_t)n * 8;
    float* dinv    = (float*)p;               p += (size_t)n * 4;
    u16*   A16     = (u16*)p;                 p += (size_t)n * HID * 2;
    u16*   B16     = (u16*)p;                 p += (size_t)n * HID * 2;
    float* pooled  = (float*)p;               p += N_GRAPHS_C * HID * 4;
    float* counts  = (float*)p;               p += N_GRAPHS_C * 4;
    int2*  pairs   = (int2*)p;                // 196*6144*8 = 9.6 MB tail region

    const int BT = 256;
    const int gridNode = (n + BT - 1) / BT;
    const int gridE2   = (nE + EPB - 1) / EPB;           // 245
    const int gridNF   = (n * HID + BT - 1) / BT;
    const int gridWave = (n + 3) / 4;
    const int gridMM2  = (n + MM2_NODES - 1) / MM2_NODES;
    const int gridFin  = (N_GRAPHS_C * HID + BT - 1) / BT;

    // CSR build (single-pass binning) + dinv
    hipMemsetAsync(gcursor, 0, 1024, stream);
    bin_pairs<<<gridE2, BT, 0, stream>>>(src, dst, gcursor, pairs, nE, nbuck);
    build_csr<<<nbuck, BT, 0, stream>>>(pairs, gcursor, csr_src, off2, dinv, n);

    // layer 1
    mm1<<<gridNF, BT, 0, stream>>>(x, W1, dinv, A16, n);
    gather_nodes<<<gridWave, BT, 0, stream>>>(A16, dinv, csr_src, off2, b1, B16, n);

    // layer 2
    mm2<<<gridMM2, BT, 0, stream>>>(B16, W2, dinv, A16, n);
    gather_nodes<<<gridWave, BT, 0, stream>>>(A16, dinv, csr_src, off2, b2, B16, n);

    // pool
    hipMemsetAsync(pooled, 0, (size_t)(N_GRAPHS_C * HID + N_GRAPHS_C) * 4, stream);
    pool<<<gridNode, BT, 0, stream>>>(B16, batch, pooled, counts, n);
    finalize<<<gridFin, BT, 0, stream>>>(pooled, counts, (float*)d_out, N_GRAPHS_C * HID);
}

// Round 7
// 228.828 us; speedup vs baseline: 8.0718x; 1.2610x over previous
//
#include <hip/hip_runtime.h>

#define HID 64
#define N_GRAPHS_C 512
#define BSHIFT 9          // 512 nodes per coarse bucket
#define CAP 6144          // bucket capacity (mean 5120 + 14 sigma)
#define EPB 4096          // edges per block in bin pass

typedef unsigned short u16;
typedef unsigned int u32;

__device__ __forceinline__ float bf2f(u16 u) {
    union { u32 i; float f; } v; v.i = ((u32)u) << 16; return v.f;
}
__device__ __forceinline__ u16 f2bf(float f) {
    union { float f; u32 i; } v; v.f = f;
    u32 x = v.i;
    return (u16)((x + 0x7fffu + ((x >> 16) & 1u)) >> 16);  // RNE
}

// ---------------- CSR build: single-pass binning, fixed-capacity buckets ----

__global__ void bin_pairs(const int* __restrict__ src, const int* __restrict__ dst,
                          int* __restrict__ gcursor, int2* __restrict__ pairs,
                          int nE, int nbuck) {
    __shared__ int lh[256];
    __shared__ int lbase[256];
    int t = threadIdx.x;
    lh[t] = 0;
    __syncthreads();
    int base = blockIdx.x * EPB;
    int sj[16], dj[16], rj[16], bj[16];
    #pragma unroll
    for (int j = 0; j < 16; ++j) {
        int e = base + j * 256 + t;
        if (e < nE) {
            sj[j] = src[e];
            dj[j] = dst[e];
            bj[j] = dj[j] >> BSHIFT;
            rj[j] = atomicAdd(&lh[bj[j]], 1);
        } else {
            bj[j] = -1;
        }
    }
    __syncthreads();
    if (t < nbuck) lbase[t] = (lh[t] > 0) ? atomicAdd(&gcursor[t], lh[t]) : 0;
    __syncthreads();
    #pragma unroll
    for (int j = 0; j < 16; ++j) {
        if (bj[j] >= 0) {
            int pos = bj[j] * CAP + lbase[bj[j]] + rj[j];
            pairs[pos] = make_int2(sj[j], dj[j]);
        }
    }
}

// One block per bucket: LDS histogram over 512 local nodes, LDS scan ->
// per-node (beg,end) + dinv + xs (pre-scaled x), then LDS-cursor csr fill.
__global__ void build_csr(const int2* __restrict__ pairs, const int* __restrict__ gcursor,
                          int* __restrict__ csr_src, int2* __restrict__ off2,
                          float* __restrict__ dinv, const float* __restrict__ x,
                          float4* __restrict__ xs, int n) {
    __shared__ int hist[512];
    __shared__ int tmp[256];
    int t = threadIdx.x;
    int b = blockIdx.x;
    int pbeg = b * CAP;
    int pend = pbeg + gcursor[b];
    hist[t] = 0; hist[t + 256] = 0;
    __syncthreads();
    int nbeg = b << BSHIFT;
    for (int i = pbeg + t; i < pend; i += 256)
        atomicAdd(&hist[pairs[i].y - nbeg], 1);
    __syncthreads();
    int v0 = hist[2 * t], v1 = hist[2 * t + 1];
    int ps = v0 + v1;
    tmp[t] = ps;
    __syncthreads();
    for (int d = 1; d < 256; d <<= 1) {
        int add = (t >= d) ? tmp[t - d] : 0;
        __syncthreads();
        tmp[t] += add;
        __syncthreads();
    }
    int pexcl = tmp[t] - ps;
    int e0 = pbeg + pexcl, e1 = e0 + v0;
    int n0 = nbeg + 2 * t, n1 = n0 + 1;
    if (n0 < n) {
        float d0 = rsqrtf((float)(v0 + 1));
        off2[n0] = make_int2(e0, e0 + v0); dinv[n0] = d0;
        xs[n0] = make_float4(x[3*n0]*d0, x[3*n0+1]*d0, x[3*n0+2]*d0, d0);
    }
    if (n1 < n) {
        float d1 = rsqrtf((float)(v1 + 1));
        off2[n1] = make_int2(e1, e1 + v1); dinv[n1] = d1;
        xs[n1] = make_float4(x[3*n1]*d1, x[3*n1+1]*d1, x[3*n1+2]*d1, d1);
    }
    hist[2 * t]     = e0;      // repurpose as fill cursors
    hist[2 * t + 1] = e1;
    __syncthreads();
    for (int i = pbeg + t; i < pend; i += 256) {
        int2 p = pairs[i];
        int pos = atomicAdd(&hist[p.y - nbeg], 1);
        csr_src[pos] = p.x;
    }
}

// ---------------- layer 1: 3-dim aggregation (thread per node) --------------
// agg4[d] = { sum_{s in N(d)} xs[s].xyz + xs[d].xyz , dinv[d] }

__global__ void agg3(const float4* __restrict__ xs, const int* __restrict__ csr_src,
                     const int2* __restrict__ off2, float4* __restrict__ agg4, int n) {
    int node = blockIdx.x * blockDim.x + threadIdx.x;
    if (node >= n) return;
    int2 be = off2[node];
    int beg = be.x, end = be.y;
    float4 self = xs[node];
    float a0 = 0.f, a1 = 0.f, a2 = 0.f;
    for (int k = beg; k < end; k += 8) {
        int e1 = end - 1;
        int idx[8];
        float4 v[8];
        #pragma unroll
        for (int j = 0; j < 8; ++j) idx[j] = csr_src[min(k + j, e1)];
        #pragma unroll
        for (int j = 0; j < 8; ++j) v[j] = xs[idx[j]];
        #pragma unroll
        for (int j = 0; j < 8; ++j) {
            if (k + j < end) { a0 += v[j].x; a1 += v[j].y; a2 += v[j].z; }
        }
    }
    agg4[node] = make_float4(a0 + self.x, a1 + self.y, a2 + self.z, self.w);
}

// expand: H1[node,f] = relu( dot3(agg4.xyz, W1[:,f]) * dinv + b1[f] )
__global__ void expand(const float4* __restrict__ agg4, const float* __restrict__ W1,
                       const float* __restrict__ b1, u16* __restrict__ H1, int n) {
    __shared__ float w[3 * HID];
    int t = threadIdx.x;
    if (t < 3 * HID) w[t] = W1[t];
    __syncthreads();
    int tid = blockIdx.x * blockDim.x + t;
    int node = tid >> 6, f = tid & 63;
    if (node < n) {
        float4 a = agg4[node];
        float v = (a.x * w[f] + a.y * w[HID + f] + a.z * w[2 * HID + f]) * a.w + b1[f];
        H1[tid] = f2bf(v > 0.0f ? v : 0.0f);
    }
}

// ---------------- layer 2 matmul: A16 = bf16((H1 @ W2) * dinv) --------------

#define MM2_NODES 16
__global__ void mm2(const u16* __restrict__ H16, const float* __restrict__ W2,
                    const float* __restrict__ dinv, u16* __restrict__ A16, int n) {
    __shared__ float w[HID * HID];
    __shared__ float h[MM2_NODES * HID];
    int t = threadIdx.x;
    for (int i = t; i < HID * HID; i += 256) w[i] = W2[i];
    int base = blockIdx.x * MM2_NODES;
    for (int i = t; i < MM2_NODES * HID; i += 256) {
        int node = base + (i >> 6);
        h[i] = (node < n) ? bf2f(H16[(size_t)node * HID + (i & 63)]) : 0.0f;
    }
    __syncthreads();
    int f = t & 63, g = t >> 6;
    float acc0 = 0.f, acc1 = 0.f, acc2 = 0.f, acc3 = 0.f;
    #pragma unroll 8
    for (int k = 0; k < HID; ++k) {
        float wk = w[k * HID + f];
        acc0 += h[(g * 4 + 0) * HID + k] * wk;
        acc1 += h[(g * 4 + 1) * HID + k] * wk;
        acc2 += h[(g * 4 + 2) * HID + k] * wk;
        acc3 += h[(g * 4 + 3) * HID + k] * wk;
    }
    float accs[4] = {acc0, acc1, acc2, acc3};
    #pragma unroll
    for (int j = 0; j < 4; ++j) {
        int node = base + g * 4 + j;
        if (node < n) A16[(size_t)node * HID + f] = f2bf(accs[j] * dinv[node]);
    }
}

// ---------------- layer-2 gather: masked 16-chunks, one wave per node -------

__global__ void gather_nodes(const u16* __restrict__ A16, const float* __restrict__ dinv,
                             const int* __restrict__ csr_src, const int2* __restrict__ off2,
                             const float* __restrict__ bias,
                             u16* __restrict__ H16, int n) {
    int node = blockIdx.x * (blockDim.x >> 6) + (threadIdx.x >> 6);
    int f = threadIdx.x & 63;
    if (node >= n) return;
    int2 be = off2[node];
    int beg = be.x, end = be.y;
    float acc = bf2f(A16[(size_t)node * HID + f]);  // self-loop (pre-scaled)
    for (int k = beg; k < end; k += 16) {
        int e1 = end - 1;
        int idx[16];
        u16 rv[16];
        #pragma unroll
        for (int j = 0; j < 16; ++j) idx[j] = csr_src[min(k + j, e1)];
        #pragma unroll
        for (int j = 0; j < 16; ++j) rv[j] = A16[(size_t)idx[j] * HID + f];
        #pragma unroll
        for (int j = 0; j < 16; ++j) acc += (k + j < end) ? bf2f(rv[j]) : 0.0f;
    }
    float v = acc * dinv[node] + bias[f];
    H16[(size_t)node * HID + f] = f2bf(v > 0.0f ? v : 0.0f);
}

// ---------------- global mean pool (batch sorted): chunked, boundary-flush --

__global__ void pool(const u16* __restrict__ H16, const int* __restrict__ batch,
                     float* __restrict__ pooled, float* __restrict__ counts, int n) {
    int f = threadIdx.x & 63, g = threadIdx.x >> 6;
    int start = (blockIdx.x * 4 + g) * 64;
    if (start >= n) return;
    int end = min(start + 64, n);
    int cur = batch[start];
    float acc = 0.0f, cnt = 0.0f;
    for (int i = start; i < end; ++i) {
        int bg = batch[i];
        if (bg != cur) {
            atomicAdd(&pooled[cur * HID + f], acc);
            if (f == 0) atomicAdd(&counts[cur], cnt);
            acc = 0.0f; cnt = 0.0f; cur = bg;
        }
        acc += bf2f(H16[(size_t)i * HID + f]);
        cnt += 1.0f;
    }
    atomicAdd(&pooled[cur * HID + f], acc);
    if (f == 0) atomicAdd(&counts[cur], cnt);
}

__global__ void finalize(const float* __restrict__ pooled, const float* __restrict__ counts,
                         float* __restrict__ out, int total) {
    int tid = blockIdx.x * blockDim.x + threadIdx.x;
    if (tid < total) {
        float c = counts[tid >> 6];
        out[tid] = pooled[tid] / fmaxf(c, 1.0f);
    }
}

// ---------------- launcher ----------------

extern "C" void kernel_launch(void* const* d_in, const int* in_sizes, int n_in,
                              void* d_out, int out_size, void* d_ws, size_t ws_size,
                              hipStream_t stream) {
    const float* x  = (const float*)d_in[0];
    const float* W1 = (const float*)d_in[1];
    const float* b1 = (const float*)d_in[2];
    const float* W2 = (const float*)d_in[3];
    const float* b2 = (const float*)d_in[4];
    const int*   ei = (const int*)d_in[5];
    const int*   batch = (const int*)d_in[6];

    const int n  = in_sizes[0] / 3;   // 100000
    const int nE = in_sizes[5] / 2;   // 1000000
    const int* src = ei;
    const int* dst = ei + nE;
    const int nbuck = (n + ((1 << BSHIFT) - 1)) >> BSHIFT;   // 196

    // workspace layout
    char* p = (char*)d_ws;
    int*    gcursor = (int*)p;                p += 1024;
    int*    csr_src = (int*)p;                p += (size_t)nbuck * CAP * 4;   // 4.8 MB
    int2*   off2    = (int2*)p;               p += (size_t)n * 8;
    float*  dinv    = (float*)p;              p += (size_t)n * 4;
    float4* xs      = (float4*)p;             p += (size_t)n * 16;
    float4* agg4    = (float4*)p;             p += (size_t)n * 16;
    u16*    H1      = (u16*)p;                p += (size_t)n * HID * 2;       // layer1 out; reused as layer2 out
    u16*    A16     = (u16*)p;                p += (size_t)n * HID * 2;       // mm2 out; pairs aliases front
    float*  pooled  = (float*)p;              p += N_GRAPHS_C * HID * 4;
    float*  counts  = (float*)p;              p += N_GRAPHS_C * 4;
    int2*   pairs   = (int2*)A16;             // 9.6 MB < 12.8 MB; dead before mm2 writes
    u16*    H2      = H1;                     // H1 dead after mm2 reads it

    const int BT = 256;
    const int gridNode = (n + BT - 1) / BT;
    const int gridE2   = (nE + EPB - 1) / EPB;           // 245
    const int gridNF   = (n * HID + BT - 1) / BT;
    const int gridWave = (n + 3) / 4;
    const int gridMM2  = (n + MM2_NODES - 1) / MM2_NODES;
    const int gridFin  = (N_GRAPHS_C * HID + BT - 1) / BT;

    // CSR build (single-pass binning) + dinv + xs
    hipMemsetAsync(gcursor, 0, 1024, stream);
    bin_pairs<<<gridE2, BT, 0, stream>>>(src, dst, gcursor, pairs, nE, nbuck);
    build_csr<<<nbuck, BT, 0, stream>>>(pairs, gcursor, csr_src, off2, dinv, x, xs, n);

    // layer 1: 3-dim aggregate, then expand to 64 features
    agg3<<<gridNode, BT, 0, stream>>>(xs, csr_src, off2, agg4, n);
    expand<<<gridNF, BT, 0, stream>>>(agg4, W1, b1, H1, n);

    // layer 2
    mm2<<<gridMM2, BT, 0, stream>>>(H1, W2, dinv, A16, n);
    gather_nodes<<<gridWave, BT, 0, stream>>>(A16, dinv, csr_src, off2, b2, H2, n);

    // pool
    hipMemsetAsync(pooled, 0, (size_t)(N_GRAPHS_C * HID + N_GRAPHS_C) * 4, stream);
    pool<<<gridNode, BT, 0, stream>>>(H2, batch, pooled, counts, n);
    finalize<<<gridFin, BT, 0, stream>>>(pooled, counts, (float*)d_out, N_GRAPHS_C * HID);
}

// Round 8
// 196.309 us; speedup vs baseline: 9.4089x; 1.1656x over previous
//
#include <hip/hip_runtime.h>

#define HID 64
#define N_GRAPHS_C 512
#define BSHIFT 9          // 512 nodes per coarse bucket
#define CAP 6144          // bucket capacity (mean 5120 + 14 sigma)
#define EPB 4096          // edges per block in bin pass

typedef unsigned short u16;
typedef unsigned int u32;

__device__ __forceinline__ float bf2f(u16 u) {
    union { u32 i; float f; } v; v.i = ((u32)u) << 16; return v.f;
}
__device__ __forceinline__ u16 f2bf(float f) {
    union { float f; u32 i; } v; v.f = f;
    u32 x = v.i;
    return (u16)((x + 0x7fffu + ((x >> 16) & 1u)) >> 16);  // RNE
}

// ---------------- CSR build: single-pass binning, packed u32 pairs ----------
// pack = (local_dst << 17) | src   (local_dst < 512 -> 9 bits, src < 131072)

__global__ void bin_pairs(const int* __restrict__ src, const int* __restrict__ dst,
                          int* __restrict__ gcursor, u32* __restrict__ pairs,
                          int nE, int nbuck) {
    __shared__ int lh[256];
    __shared__ int lbase[256];
    int t = threadIdx.x;
    lh[t] = 0;
    __syncthreads();
    int base = blockIdx.x * EPB;
    u32 pk[16]; int rj[16], bj[16];
    #pragma unroll
    for (int j = 0; j < 16; ++j) {
        int e = base + j * 256 + t;
        if (e < nE) {
            int s = src[e], d = dst[e];
            bj[j] = d >> BSHIFT;
            pk[j] = ((u32)(d & 511) << 17) | (u32)s;
            rj[j] = atomicAdd(&lh[bj[j]], 1);
        } else {
            bj[j] = -1;
        }
    }
    __syncthreads();
    if (t < nbuck) lbase[t] = (lh[t] > 0) ? atomicAdd(&gcursor[t], lh[t]) : 0;
    __syncthreads();
    #pragma unroll
    for (int j = 0; j < 16; ++j) {
        if (bj[j] >= 0) {
            int pos = bj[j] * CAP + lbase[bj[j]] + rj[j];
            pairs[pos] = pk[j];
        }
    }
}

// One block per bucket: LDS histogram over 512 local nodes, LDS scan ->
// per-node (beg,end) + dinv + xs (pre-scaled x), then LDS-cursor csr fill.
__global__ void build_csr(const u32* __restrict__ pairs, const int* __restrict__ gcursor,
                          int* __restrict__ csr_src, int2* __restrict__ off2,
                          float* __restrict__ dinv, const float* __restrict__ x,
                          float4* __restrict__ xs, int n) {
    __shared__ int hist[512];
    __shared__ int tmp[256];
    int t = threadIdx.x;
    int b = blockIdx.x;
    int pbeg = b * CAP;
    int pend = pbeg + gcursor[b];
    hist[t] = 0; hist[t + 256] = 0;
    __syncthreads();
    int nbeg = b << BSHIFT;
    for (int i = pbeg + t; i < pend; i += 256)
        atomicAdd(&hist[pairs[i] >> 17], 1);
    __syncthreads();
    int v0 = hist[2 * t], v1 = hist[2 * t + 1];
    int ps = v0 + v1;
    tmp[t] = ps;
    __syncthreads();
    for (int d = 1; d < 256; d <<= 1) {
        int add = (t >= d) ? tmp[t - d] : 0;
        __syncthreads();
        tmp[t] += add;
        __syncthreads();
    }
    int pexcl = tmp[t] - ps;
    int e0 = pbeg + pexcl, e1 = e0 + v0;
    int n0 = nbeg + 2 * t, n1 = n0 + 1;
    if (n0 < n) {
        float d0 = rsqrtf((float)(v0 + 1));
        off2[n0] = make_int2(e0, e0 + v0); dinv[n0] = d0;
        xs[n0] = make_float4(x[3*n0]*d0, x[3*n0+1]*d0, x[3*n0+2]*d0, d0);
    }
    if (n1 < n) {
        float d1 = rsqrtf((float)(v1 + 1));
        off2[n1] = make_int2(e1, e1 + v1); dinv[n1] = d1;
        xs[n1] = make_float4(x[3*n1]*d1, x[3*n1+1]*d1, x[3*n1+2]*d1, d1);
    }
    hist[2 * t]     = e0;      // repurpose as fill cursors
    hist[2 * t + 1] = e1;
    __syncthreads();
    for (int i = pbeg + t; i < pend; i += 256) {
        u32 p = pairs[i];
        int pos = atomicAdd(&hist[p >> 17], 1);
        csr_src[pos] = (int)(p & 0x1FFFFu);
    }
}

// ---------------- layer 1: 3-dim aggregation (thread per node) --------------

__global__ void agg3(const float4* __restrict__ xs, const int* __restrict__ csr_src,
                     const int2* __restrict__ off2, float4* __restrict__ agg4, int n) {
    int node = blockIdx.x * blockDim.x + threadIdx.x;
    if (node >= n) return;
    int2 be = off2[node];
    int beg = be.x, end = be.y;
    float4 self = xs[node];
    float a0 = 0.f, a1 = 0.f, a2 = 0.f;
    for (int k = beg; k < end; k += 8) {
        int e1 = end - 1;
        int idx[8];
        float4 v[8];
        #pragma unroll
        for (int j = 0; j < 8; ++j) idx[j] = csr_src[min(k + j, e1)];
        #pragma unroll
        for (int j = 0; j < 8; ++j) v[j] = xs[idx[j]];
        #pragma unroll
        for (int j = 0; j < 8; ++j) {
            if (k + j < end) { a0 += v[j].x; a1 += v[j].y; a2 += v[j].z; }
        }
    }
    agg4[node] = make_float4(a0 + self.x, a1 + self.y, a2 + self.z, self.w);
}

// ---------------- fused expand + layer-2 matmul ----------------
// h[node,f] = relu(dot3(agg4.xyz, W1[:,f]) * dinv + b1[f])   (in LDS, fp32)
// A16[node,f] = bf16( (h @ W2)[node,f] * dinv[node] )

#define MM2_NODES 16
__global__ void mm2f(const float4* __restrict__ agg4, const float* __restrict__ W1,
                     const float* __restrict__ b1, const float* __restrict__ W2,
                     u16* __restrict__ A16, int n) {
    __shared__ float w[HID * HID];        // 16 KB
    __shared__ float h[MM2_NODES * HID];  // 4 KB
    __shared__ float dd[MM2_NODES];
    int t = threadIdx.x;
    for (int i = t; i < HID * HID; i += 256) w[i] = W2[i];
    int base = blockIdx.x * MM2_NODES;
    for (int i = t; i < MM2_NODES * HID; i += 256) {
        int node = base + (i >> 6);
        int f = i & 63;
        float hv = 0.0f;
        if (node < n) {
            float4 a = agg4[node];
            float v = (a.x * W1[f] + a.y * W1[HID + f] + a.z * W1[2 * HID + f]) * a.w + b1[f];
            hv = v > 0.0f ? v : 0.0f;
            if (f == 0) dd[i >> 6] = a.w;
        }
        h[i] = hv;
    }
    __syncthreads();
    int f = t & 63, g = t >> 6;
    float acc0 = 0.f, acc1 = 0.f, acc2 = 0.f, acc3 = 0.f;
    #pragma unroll 8
    for (int k = 0; k < HID; ++k) {
        float wk = w[k * HID + f];
        acc0 += h[(g * 4 + 0) * HID + k] * wk;
        acc1 += h[(g * 4 + 1) * HID + k] * wk;
        acc2 += h[(g * 4 + 2) * HID + k] * wk;
        acc3 += h[(g * 4 + 3) * HID + k] * wk;
    }
    float accs[4] = {acc0, acc1, acc2, acc3};
    #pragma unroll
    for (int j = 0; j < 4; ++j) {
        int node = base + g * 4 + j;
        if (node < n) A16[(size_t)node * HID + f] = f2bf(accs[j] * dd[g * 4 + j]);
    }
}

// ---------------- layer-2 gather: 2 nodes/wave, ushort2 lanes, shfl idx -----

__global__ void gather_nodes(const u16* __restrict__ A16, const float* __restrict__ dinv,
                             const int* __restrict__ csr_src, const int2* __restrict__ off2,
                             const float* __restrict__ bias,
                             u16* __restrict__ H16, int n) {
    int t = threadIdx.x;
    int wave = t >> 6;                 // wave in block (0..3)
    int half = (t >> 5) & 1;           // node slot within wave
    int m = t & 31;                    // feature pair index
    int hbase = t & 32;                // shfl base lane of my half-wave
    int node = (blockIdx.x * 4 + wave) * 2 + half;
    if (node >= n) return;
    int2 be = off2[node];
    int beg = be.x, end = be.y;
    float2 bb = *(const float2*)(bias + 2 * m);
    u32 selfrow = *(const u32*)(A16 + (size_t)node * HID + 2 * m);
    float acc0 = bf2f((u16)(selfrow & 0xffffu));
    float acc1 = bf2f((u16)(selfrow >> 16));
    for (int k = beg; k < end; k += 32) {
        int nIdx = min(32, end - k);
        int myIdx = 0;
        if (m < nIdx) myIdx = csr_src[k + m];     // coalesced: 32 idx per half
        for (int j0 = 0; j0 < nIdx; j0 += 8) {
            int ss[8]; u32 rows[8];
            #pragma unroll
            for (int j = 0; j < 8; ++j)
                ss[j] = __shfl(myIdx, hbase + min(j0 + j, nIdx - 1), 64);
            #pragma unroll
            for (int j = 0; j < 8; ++j)
                rows[j] = *(const u32*)(A16 + (size_t)ss[j] * HID + 2 * m);
            #pragma unroll
            for (int j = 0; j < 8; ++j) {
                bool ok = (j0 + j < nIdx);
                u32 r = rows[j];
                acc0 += ok ? bf2f((u16)(r & 0xffffu)) : 0.0f;
                acc1 += ok ? bf2f((u16)(r >> 16)) : 0.0f;
            }
        }
    }
    float ddv = dinv[node];
    float v0 = acc0 * ddv + bb.x;
    float v1 = acc1 * ddv + bb.y;
    v0 = v0 > 0.0f ? v0 : 0.0f;
    v1 = v1 > 0.0f ? v1 : 0.0f;
    *(u32*)(H16 + (size_t)node * HID + 2 * m) = (u32)f2bf(v0) | ((u32)f2bf(v1) << 16);
}

// ---------------- global mean pool (batch sorted): chunked, boundary-flush --

__global__ void pool(const u16* __restrict__ H16, const int* __restrict__ batch,
                     float* __restrict__ pooled, float* __restrict__ counts, int n) {
    int f = threadIdx.x & 63, g = threadIdx.x >> 6;
    int start = (blockIdx.x * 4 + g) * 64;
    if (start >= n) return;
    int end = min(start + 64, n);
    int cur = batch[start];
    float acc = 0.0f, cnt = 0.0f;
    for (int i = start; i < end; ++i) {
        int bg = batch[i];
        if (bg != cur) {
            atomicAdd(&pooled[cur * HID + f], acc);
            if (f == 0) atomicAdd(&counts[cur], cnt);
            acc = 0.0f; cnt = 0.0f; cur = bg;
        }
        acc += bf2f(H16[(size_t)i * HID + f]);
        cnt += 1.0f;
    }
    atomicAdd(&pooled[cur * HID + f], acc);
    if (f == 0) atomicAdd(&counts[cur], cnt);
}

__global__ void finalize(const float* __restrict__ pooled, const float* __restrict__ counts,
                         float* __restrict__ out, int total) {
    int tid = blockIdx.x * blockDim.x + threadIdx.x;
    if (tid < total) {
        float c = counts[tid >> 6];
        out[tid] = pooled[tid] / fmaxf(c, 1.0f);
    }
}

// ---------------- launcher ----------------

extern "C" void kernel_launch(void* const* d_in, const int* in_sizes, int n_in,
                              void* d_out, int out_size, void* d_ws, size_t ws_size,
                              hipStream_t stream) {
    const float* x  = (const float*)d_in[0];
    const float* W1 = (const float*)d_in[1];
    const float* b1 = (const float*)d_in[2];
    const float* W2 = (const float*)d_in[3];
    const float* b2 = (const float*)d_in[4];
    const int*   ei = (const int*)d_in[5];
    const int*   batch = (const int*)d_in[6];

    const int n  = in_sizes[0] / 3;   // 100000
    const int nE = in_sizes[5] / 2;   // 1000000
    const int* src = ei;
    const int* dst = ei + nE;
    const int nbuck = (n + ((1 << BSHIFT) - 1)) >> BSHIFT;   // 196

    // workspace layout
    char* p = (char*)d_ws;
    int*    gcursor = (int*)p;                p += 1024;
    int*    csr_src = (int*)p;                p += (size_t)nbuck * CAP * 4;   // 4.8 MB
    int2*   off2    = (int2*)p;               p += (size_t)n * 8;
    float*  dinv    = (float*)p;              p += (size_t)n * 4;
    float4* xs      = (float4*)p;             p += (size_t)n * 16;
    float4* agg4    = (float4*)p;             p += (size_t)n * 16;
    u16*    A16     = (u16*)p;                p += (size_t)n * HID * 2;       // mm2f out; pairs aliases front
    u16*    H2      = (u16*)p;                p += (size_t)n * HID * 2;       // gather out
    float*  pooled  = (float*)p;              p += N_GRAPHS_C * HID * 4;
    float*  counts  = (float*)p;              p += N_GRAPHS_C * 4;
    u32*    pairs   = (u32*)A16;              // 4.8 MB < 12.8 MB; dead before mm2f writes

    const int BT = 256;
    const int gridNode = (n + BT - 1) / BT;
    const int gridE2   = (nE + EPB - 1) / EPB;           // 245
    const int gridWave = (n + 7) / 8;                    // 8 nodes/block (2/wave)
    const int gridMM2  = (n + MM2_NODES - 1) / MM2_NODES;
    const int gridFin  = (N_GRAPHS_C * HID + BT - 1) / BT;

    // CSR build (single-pass binning) + dinv + xs
    hipMemsetAsync(gcursor, 0, 1024, stream);
    bin_pairs<<<gridE2, BT, 0, stream>>>(src, dst, gcursor, pairs, nE, nbuck);
    build_csr<<<nbuck, BT, 0, stream>>>(pairs, gcursor, csr_src, off2, dinv, x, xs, n);

    // layer 1 aggregate (3-dim), then fused expand + layer-2 matmul
    agg3<<<gridNode, BT, 0, stream>>>(xs, csr_src, off2, agg4, n);
    mm2f<<<gridMM2, BT, 0, stream>>>(agg4, W1, b1, W2, A16, n);

    // layer-2 gather
    gather_nodes<<<gridWave, BT, 0, stream>>>(A16, dinv, csr_src, off2, b2, H2, n);

    // pool
    hipMemsetAsync(pooled, 0, (size_t)(N_GRAPHS_C * HID + N_GRAPHS_C) * 4, stream);
    pool<<<gridNode, BT, 0, stream>>>(H2, batch, pooled, counts, n);
    finalize<<<gridFin, BT, 0, stream>>>(pooled, counts, (float*)d_out, N_GRAPHS_C * HID);
}